// Round 1
// baseline (4256.736 us; speedup 1.0000x reference)
//
#include <hip/hip_runtime.h>
#include <math.h>

#define S_LEN 2048
#define NBATCH 2
#define NHEADS 16
#define HD 64
#define DM 1024
#define NROWS (NBATCH * S_LEN)   // 4096

// ---------------- projection GEMM (+bias, optional RoPE, transposed store) ----
// A: [NROWS][DM] row-major, W: [DM][DM] row-major.
// Output layout: [b][h][s][d]  -> outT[((n*NHEADS+h)*S_LEN + s)*HD + d]
// Column tile (64 wide) == exactly one head, so h = blockIdx.x.
template<int ROPE>
__global__ __launch_bounds__(256)
void proj_kernel(const float* __restrict__ A,
                 const float* __restrict__ W,
                 const float* __restrict__ bias,
                 const float* __restrict__ cosp,   // [S][32]
                 const float* __restrict__ sinp,   // [S][32]
                 float* __restrict__ outT)
{
    __shared__ float As[64][17];
    __shared__ float Bs[16][68];
    const int tx = threadIdx.x, ty = threadIdx.y;
    const int tid = ty * 16 + tx;
    const int bx = blockIdx.x;   // col tile == head
    const int by = blockIdx.y;   // row tile
    const int row0 = by * 64, col0 = bx * 64;
    float acc[4][4] = {};

    for (int kt = 0; kt < DM; kt += 16) {
        // stage A: 64 rows x 16 k
        {
            const int idx = tid * 4;
            const int r = idx >> 4, k = idx & 15;
            const float4 v = *(const float4*)(A + (long)(row0 + r) * DM + kt + k);
            As[r][k + 0] = v.x; As[r][k + 1] = v.y; As[r][k + 2] = v.z; As[r][k + 3] = v.w;
        }
        // stage B: 16 k x 64 cols
        {
            const int idx = tid * 4;
            const int k = idx >> 6, c = idx & 63;
            const float4 v = *(const float4*)(W + (long)(kt + k) * DM + col0 + c);
            Bs[k][c + 0] = v.x; Bs[k][c + 1] = v.y; Bs[k][c + 2] = v.z; Bs[k][c + 3] = v.w;
        }
        __syncthreads();
        #pragma unroll
        for (int k = 0; k < 16; ++k) {
            float a[4], b[4];
            #pragma unroll
            for (int i = 0; i < 4; ++i) a[i] = As[ty * 4 + i][k];
            #pragma unroll
            for (int j = 0; j < 4; ++j) b[j] = Bs[k][tx * 4 + j];
            #pragma unroll
            for (int i = 0; i < 4; ++i)
                #pragma unroll
                for (int j = 0; j < 4; ++j)
                    acc[i][j] += a[i] * b[j];
        }
        __syncthreads();
    }

    const int h = bx;
    #pragma unroll
    for (int i = 0; i < 4; ++i) {
        const int row = row0 + ty * 4 + i;
        const int n = row >> 11;               // row / S_LEN
        const int s = row & (S_LEN - 1);
        float v0 = acc[i][0] + bias[col0 + tx * 4 + 0];
        float v1 = acc[i][1] + bias[col0 + tx * 4 + 1];
        float v2 = acc[i][2] + bias[col0 + tx * 4 + 2];
        float v3 = acc[i][3] + bias[col0 + tx * 4 + 3];
        if (ROPE) {
            const int f0 = tx * 2, f1 = tx * 2 + 1;
            const float c0 = cosp[s * 32 + f0], sn0 = sinp[s * 32 + f0];
            const float c1 = cosp[s * 32 + f1], sn1 = sinp[s * 32 + f1];
            const float o0 = v0 * c0 - v1 * sn0;
            const float o1 = v0 * sn0 + v1 * c0;
            const float o2 = v2 * c1 - v3 * sn1;
            const float o3 = v2 * sn1 + v3 * c1;
            v0 = o0; v1 = o1; v2 = o2; v3 = o3;
        }
        float* dst = outT + (((long)(n * NHEADS + h) * S_LEN + s) * HD + tx * 4);
        dst[0] = v0; dst[1] = v1; dst[2] = v2; dst[3] = v3;
    }
}

// ---------------- attention: one block per (b,h,q-row) -----------------------
__global__ __launch_bounds__(256)
void attn_kernel(const float* __restrict__ qT,
                 const float* __restrict__ kT,
                 const float* __restrict__ vT,
                 float* __restrict__ attn,   // [bh][q][k]
                 float* __restrict__ ctx)    // [bh][s][d]
{
    const int g = blockIdx.x;                // bh*S + qrow
    const int bh = g >> 11;                  // g / S_LEN
    const int qrow = g & (S_LEN - 1);
    const int tid = threadIdx.x;

    __shared__ float sc[S_LEN];
    __shared__ float qv[HD];
    __shared__ float red[4][HD];
    __shared__ float rmax[4], rsum[4];

    if (tid < HD) qv[tid] = qT[((long)bh * S_LEN + qrow) * HD + tid];
    __syncthreads();

    const float scale = 0.125f;              // 1/sqrt(64)
    float lmax = -1e30f;
    for (int j = tid; j <= qrow; j += 256) {
        const float4* kr = (const float4*)(kT + ((long)bh * S_LEN + j) * HD);
        float dot = 0.f;
        #pragma unroll
        for (int t = 0; t < 16; ++t) {
            const float4 kk = kr[t];
            dot += qv[4 * t + 0] * kk.x + qv[4 * t + 1] * kk.y
                 + qv[4 * t + 2] * kk.z + qv[4 * t + 3] * kk.w;
        }
        dot *= scale;
        sc[j] = dot;
        lmax = fmaxf(lmax, dot);
    }
    #pragma unroll
    for (int off = 32; off; off >>= 1) lmax = fmaxf(lmax, __shfl_xor(lmax, off));
    if ((tid & 63) == 0) rmax[tid >> 6] = lmax;
    __syncthreads();
    const float m = fmaxf(fmaxf(rmax[0], rmax[1]), fmaxf(rmax[2], rmax[3]));

    float lsum = 0.f;
    for (int j = tid; j <= qrow; j += 256) {
        const float e = expf(sc[j] - m);
        sc[j] = e;
        lsum += e;
    }
    #pragma unroll
    for (int off = 32; off; off >>= 1) lsum += __shfl_xor(lsum, off);
    if ((tid & 63) == 0) rsum[tid >> 6] = lsum;
    __syncthreads();
    const float inv = 1.f / (rsum[0] + rsum[1] + rsum[2] + rsum[3]);

    float* arow = attn + (long)g * S_LEN;
    for (int j = tid; j < S_LEN; j += 256) {
        const float val = (j <= qrow) ? sc[j] * inv : 0.f;
        arow[j] = val;
        sc[j] = val;
    }
    __syncthreads();

    const int d = tid & 63, grp = tid >> 6;
    float acc = 0.f;
    for (int j = grp; j <= qrow; j += 4)
        acc += sc[j] * vT[((long)bh * S_LEN + j) * HD + d];
    red[grp][d] = acc;
    __syncthreads();
    if (tid < HD) {
        const float r = red[0][tid] + red[1][tid] + red[2][tid] + red[3][tid];
        ctx[((long)bh * S_LEN + qrow) * HD + tid] = r;
    }
}

// ---------------- output projection GEMM -------------------------------------
// hidden[row][c] = sum_k ctx_row[k] * Wo[k][c] + bo[c],
// ctx_row[k] with k = h*64+d lives at ctx[((n*NHEADS+h)*S_LEN + s)*HD + d].
__global__ __launch_bounds__(256)
void outproj_kernel(const float* __restrict__ ctx,
                    const float* __restrict__ Wo,
                    const float* __restrict__ bo,
                    float* __restrict__ out)
{
    __shared__ float As[64][17];
    __shared__ float Bs[16][68];
    const int tx = threadIdx.x, ty = threadIdx.y;
    const int tid = ty * 16 + tx;
    const int bx = blockIdx.x, by = blockIdx.y;
    const int row0 = by * 64, col0 = bx * 64;
    float acc[4][4] = {};

    for (int kt = 0; kt < DM; kt += 16) {
        {
            const int idx = tid * 4;
            const int r = idx >> 4, kl = idx & 15;
            const int row = row0 + r;
            const int n = row >> 11, s = row & (S_LEN - 1);
            const int kk = kt + kl;                // 16-chunk never crosses a head
            const int h = kk >> 6, d = kk & 63;
            const float4 v = *(const float4*)(ctx + (((long)(n * NHEADS + h) * S_LEN + s) * HD + d));
            As[r][kl + 0] = v.x; As[r][kl + 1] = v.y; As[r][kl + 2] = v.z; As[r][kl + 3] = v.w;
        }
        {
            const int idx = tid * 4;
            const int k = idx >> 6, c = idx & 63;
            const float4 v = *(const float4*)(Wo + (long)(kt + k) * DM + col0 + c);
            Bs[k][c + 0] = v.x; Bs[k][c + 1] = v.y; Bs[k][c + 2] = v.z; Bs[k][c + 3] = v.w;
        }
        __syncthreads();
        #pragma unroll
        for (int k = 0; k < 16; ++k) {
            float a[4], b[4];
            #pragma unroll
            for (int i = 0; i < 4; ++i) a[i] = As[ty * 4 + i][k];
            #pragma unroll
            for (int j = 0; j < 4; ++j) b[j] = Bs[k][tx * 4 + j];
            #pragma unroll
            for (int i = 0; i < 4; ++i)
                #pragma unroll
                for (int j = 0; j < 4; ++j)
                    acc[i][j] += a[i] * b[j];
        }
        __syncthreads();
    }

    #pragma unroll
    for (int i = 0; i < 4; ++i) {
        const int row = row0 + ty * 4 + i;
        float* dst = out + (long)row * DM + col0 + tx * 4;
        dst[0] = acc[i][0] + bo[col0 + tx * 4 + 0];
        dst[1] = acc[i][1] + bo[col0 + tx * 4 + 1];
        dst[2] = acc[i][2] + bo[col0 + tx * 4 + 2];
        dst[3] = acc[i][3] + bo[col0 + tx * 4 + 3];
    }
}

extern "C" void kernel_launch(void* const* d_in, const int* in_sizes, int n_in,
                              void* d_out, int out_size, void* d_ws, size_t ws_size,
                              hipStream_t stream) {
    const float* x    = (const float*)d_in[0];
    const float* Wq   = (const float*)d_in[1];
    const float* bq   = (const float*)d_in[2];
    const float* Wk   = (const float*)d_in[3];
    const float* bk   = (const float*)d_in[4];
    const float* Wv   = (const float*)d_in[5];
    const float* bv   = (const float*)d_in[6];
    const float* Wo   = (const float*)d_in[7];
    const float* bo   = (const float*)d_in[8];
    const float* cosp = (const float*)d_in[9];
    const float* sinp = (const float*)d_in[10];
    // d_in[11] = mask (causal tril) — implemented analytically.

    float* out = (float*)d_out;
    float* ws  = (float*)d_ws;

    float* qT  = ws;                       // 4,194,304 floats
    float* kT  = ws + 4194304;
    float* vT  = ws + 8388608;
    float* ctx = ws + 12582912;            // total 64 MB ws

    float* hidden = out;                   // [NROWS][DM]
    float* attn   = out + (long)NROWS * DM;

    dim3 gblk(16, 16);
    dim3 ggrid(DM / 64, NROWS / 64);
    hipLaunchKernelGGL((proj_kernel<1>), ggrid, gblk, 0, stream, x, Wq, bq, cosp, sinp, qT);
    hipLaunchKernelGGL((proj_kernel<1>), ggrid, gblk, 0, stream, x, Wk, bk, cosp, sinp, kT);
    hipLaunchKernelGGL((proj_kernel<0>), ggrid, gblk, 0, stream, x, Wv, bv, cosp, sinp, vT);

    attn_kernel<<<NBATCH * NHEADS * S_LEN, 256, 0, stream>>>(qT, kT, vT, attn, ctx);

    outproj_kernel<<<ggrid, gblk, 0, stream>>>(ctx, Wo, bo, hidden);
}

// Round 2
// 1391.800 us; speedup vs baseline: 3.0584x; 3.0584x over previous
//
#include <hip/hip_runtime.h>
#include <math.h>

#define S_LEN 2048
#define NBATCH 2
#define NHEADS 16
#define HD 64
#define DM 1024
#define NROWS (NBATCH * S_LEN)   // 4096
#define PADW 68                  // padded LDS row stride (words) for 64-wide tiles

// ---------------- projection GEMM (+bias, optional RoPE, transposed store) ----
template<int ROPE>
__global__ __launch_bounds__(256)
void proj_kernel(const float* __restrict__ A,
                 const float* __restrict__ W,
                 const float* __restrict__ bias,
                 const float* __restrict__ cosp,   // [S][32]
                 const float* __restrict__ sinp,   // [S][32]
                 float* __restrict__ outT)
{
    __shared__ float As[64][17];
    __shared__ float Bs[16][68];
    const int tx = threadIdx.x, ty = threadIdx.y;
    const int tid = ty * 16 + tx;
    const int bx = blockIdx.x;   // col tile == head
    const int by = blockIdx.y;   // row tile
    const int row0 = by * 64, col0 = bx * 64;
    float acc[4][4] = {};

    for (int kt = 0; kt < DM; kt += 16) {
        {
            const int idx = tid * 4;
            const int r = idx >> 4, k = idx & 15;
            const float4 v = *(const float4*)(A + (long)(row0 + r) * DM + kt + k);
            As[r][k + 0] = v.x; As[r][k + 1] = v.y; As[r][k + 2] = v.z; As[r][k + 3] = v.w;
        }
        {
            const int idx = tid * 4;
            const int k = idx >> 6, c = idx & 63;
            const float4 v = *(const float4*)(W + (long)(kt + k) * DM + col0 + c);
            Bs[k][c + 0] = v.x; Bs[k][c + 1] = v.y; Bs[k][c + 2] = v.z; Bs[k][c + 3] = v.w;
        }
        __syncthreads();
        #pragma unroll
        for (int k = 0; k < 16; ++k) {
            float a[4], b[4];
            #pragma unroll
            for (int i = 0; i < 4; ++i) a[i] = As[ty * 4 + i][k];
            #pragma unroll
            for (int j = 0; j < 4; ++j) b[j] = Bs[k][tx * 4 + j];
            #pragma unroll
            for (int i = 0; i < 4; ++i)
                #pragma unroll
                for (int j = 0; j < 4; ++j)
                    acc[i][j] += a[i] * b[j];
        }
        __syncthreads();
    }

    const int h = bx;
    #pragma unroll
    for (int i = 0; i < 4; ++i) {
        const int row = row0 + ty * 4 + i;
        const int n = row >> 11;
        const int s = row & (S_LEN - 1);
        float v0 = acc[i][0] + bias[col0 + tx * 4 + 0];
        float v1 = acc[i][1] + bias[col0 + tx * 4 + 1];
        float v2 = acc[i][2] + bias[col0 + tx * 4 + 2];
        float v3 = acc[i][3] + bias[col0 + tx * 4 + 3];
        if (ROPE) {
            const int f0 = tx * 2, f1 = tx * 2 + 1;
            const float c0 = cosp[s * 32 + f0], sn0 = sinp[s * 32 + f0];
            const float c1 = cosp[s * 32 + f1], sn1 = sinp[s * 32 + f1];
            const float o0 = v0 * c0 - v1 * sn0;
            const float o1 = v0 * sn0 + v1 * c0;
            const float o2 = v2 * c1 - v3 * sn1;
            const float o3 = v2 * sn1 + v3 * c1;
            v0 = o0; v1 = o1; v2 = o2; v3 = o3;
        }
        float* dst = outT + (((long)(n * NHEADS + h) * S_LEN + s) * HD + tx * 4);
        dst[0] = v0; dst[1] = v1; dst[2] = v2; dst[3] = v3;
    }
}

// ---------------- tiled attention: block per (bh, 64-query tile) -------------
// qT/kT/vT: [bh][s][d]. attn: [bh][q][k]. ctx: [bh][s][d].
// 256 threads; thread (tx,ty) owns rows 4ty+i, cols 4tx+j of the 64x64 tile.
// Two passes over k-tiles: pass1 = online row max/sum; pass2 = normalized P
// (written to global + LDS transposed) and PV accumulation.
__global__ __launch_bounds__(256)
void attn_tiled(const float* __restrict__ qT,
                const float* __restrict__ kT,
                const float* __restrict__ vT,
                float* __restrict__ attn,
                float* __restrict__ ctx)
{
    const int bh = blockIdx.x & 31;
    const int qt = 31 - (blockIdx.x >> 5);   // biggest tiles dispatched first
    const int tid = threadIdx.x;
    const int tx = tid & 15, ty = tid >> 4;
    const int c4 = tid & 15, r0 = tid >> 4;  // staging coords

    __shared__ float Qs[64 * PADW];          // Q transposed: [d][qr]
    __shared__ float KVs[64 * PADW];         // K transposed [d][kc]  /  V [kc][d]
    __shared__ float Ps[64 * PADW];          // P transposed: [kc][qr]

    const long qbase = ((long)bh * S_LEN + qt * 64) * HD;

    // stage Q transposed
    #pragma unroll
    for (int it = 0; it < 4; ++it) {
        const int r = r0 + 16 * it;
        const float4 v = *(const float4*)(qT + qbase + (long)r * HD + c4 * 4);
        Qs[(c4 * 4 + 0) * PADW + r] = v.x;
        Qs[(c4 * 4 + 1) * PADW + r] = v.y;
        Qs[(c4 * 4 + 2) * PADW + r] = v.z;
        Qs[(c4 * 4 + 3) * PADW + r] = v.w;
    }

    float m_r[4], l_r[4];
    #pragma unroll
    for (int i = 0; i < 4; ++i) { m_r[i] = -1e30f; l_r[i] = 0.f; }

    __syncthreads();

    // ---------------- pass 1: online row max & sum ----------------
    for (int kt = 0; kt <= qt; ++kt) {
        const long kbase = ((long)bh * S_LEN + kt * 64) * HD;
        #pragma unroll
        for (int it = 0; it < 4; ++it) {
            const int r = r0 + 16 * it;
            const float4 v = *(const float4*)(kT + kbase + (long)r * HD + c4 * 4);
            KVs[(c4 * 4 + 0) * PADW + r] = v.x;
            KVs[(c4 * 4 + 1) * PADW + r] = v.y;
            KVs[(c4 * 4 + 2) * PADW + r] = v.z;
            KVs[(c4 * 4 + 3) * PADW + r] = v.w;
        }
        __syncthreads();

        float acc[4][4] = {};
        #pragma unroll 8
        for (int d = 0; d < 64; ++d) {
            const float4 af = *(const float4*)(Qs + d * PADW + 4 * ty);
            const float4 bf = *(const float4*)(KVs + d * PADW + 4 * tx);
            const float a[4] = {af.x, af.y, af.z, af.w};
            const float b[4] = {bf.x, bf.y, bf.z, bf.w};
            #pragma unroll
            for (int i = 0; i < 4; ++i)
                #pragma unroll
                for (int j = 0; j < 4; ++j)
                    acc[i][j] += a[i] * b[j];
        }

        const bool diag = (kt == qt);
        #pragma unroll
        for (int i = 0; i < 4; ++i) {
            float tmax = -1e30f;
            #pragma unroll
            for (int j = 0; j < 4; ++j) {
                float s = acc[i][j] * 0.125f;
                if (diag && (4 * tx + j) > (4 * ty + i)) s = -1e30f;
                acc[i][j] = s;
                tmax = fmaxf(tmax, s);
            }
            #pragma unroll
            for (int off = 1; off < 16; off <<= 1)
                tmax = fmaxf(tmax, __shfl_xor(tmax, off));
            const float m_new = fmaxf(m_r[i], tmax);
            float psum = 0.f;
            #pragma unroll
            for (int j = 0; j < 4; ++j)
                psum += __expf(acc[i][j] - m_new);
            #pragma unroll
            for (int off = 1; off < 16; off <<= 1)
                psum += __shfl_xor(psum, off);
            l_r[i] = l_r[i] * __expf(m_r[i] - m_new) + psum;
            m_r[i] = m_new;
        }
        __syncthreads();   // before next K restage
    }

    float invl[4];
    #pragma unroll
    for (int i = 0; i < 4; ++i) invl[i] = 1.f / l_r[i];

    // ---------------- pass 2: normalized P -> attn + PV -> ctx ----------------
    float o[4][4] = {};
    const long abase = ((long)bh * S_LEN + qt * 64) * S_LEN;

    for (int kt = 0; kt < 32; ++kt) {
        if (kt > qt) {   // upper triangle: zeros (block-uniform branch)
            const float4 z = make_float4(0.f, 0.f, 0.f, 0.f);
            #pragma unroll
            for (int i = 0; i < 4; ++i)
                *(float4*)(attn + abase + (long)(4 * ty + i) * S_LEN + kt * 64 + 4 * tx) = z;
            continue;
        }
        const long kbase = ((long)bh * S_LEN + kt * 64) * HD;
        // stage K transposed
        #pragma unroll
        for (int it = 0; it < 4; ++it) {
            const int r = r0 + 16 * it;
            const float4 v = *(const float4*)(kT + kbase + (long)r * HD + c4 * 4);
            KVs[(c4 * 4 + 0) * PADW + r] = v.x;
            KVs[(c4 * 4 + 1) * PADW + r] = v.y;
            KVs[(c4 * 4 + 2) * PADW + r] = v.z;
            KVs[(c4 * 4 + 3) * PADW + r] = v.w;
        }
        __syncthreads();

        float acc[4][4] = {};
        #pragma unroll 8
        for (int d = 0; d < 64; ++d) {
            const float4 af = *(const float4*)(Qs + d * PADW + 4 * ty);
            const float4 bf = *(const float4*)(KVs + d * PADW + 4 * tx);
            const float a[4] = {af.x, af.y, af.z, af.w};
            const float b[4] = {bf.x, bf.y, bf.z, bf.w};
            #pragma unroll
            for (int i = 0; i < 4; ++i)
                #pragma unroll
                for (int j = 0; j < 4; ++j)
                    acc[i][j] += a[i] * b[j];
        }

        const bool diag = (kt == qt);
        #pragma unroll
        for (int i = 0; i < 4; ++i) {
            float p[4];
            #pragma unroll
            for (int j = 0; j < 4; ++j) {
                const float s = acc[i][j] * 0.125f;
                const bool msk = diag && (4 * tx + j) > (4 * ty + i);
                const float pp = msk ? 0.f : __expf(s - m_r[i]) * invl[i];
                p[j] = pp;
                Ps[(4 * tx + j) * PADW + 4 * ty + i] = pp;
            }
            *(float4*)(attn + abase + (long)(4 * ty + i) * S_LEN + kt * 64 + 4 * tx)
                = make_float4(p[0], p[1], p[2], p[3]);
        }
        __syncthreads();   // P visible; K-tile no longer needed

        // stage V (natural [kc][d] layout) into the shared K/V buffer
        #pragma unroll
        for (int it = 0; it < 4; ++it) {
            const int r = r0 + 16 * it;
            const float4 v = *(const float4*)(vT + kbase + (long)r * HD + c4 * 4);
            *(float4*)(KVs + r * PADW + c4 * 4) = v;
        }
        __syncthreads();

        #pragma unroll 8
        for (int kc = 0; kc < 64; ++kc) {
            const float4 af = *(const float4*)(Ps + kc * PADW + 4 * ty);
            const float4 bf = *(const float4*)(KVs + kc * PADW + 4 * tx);
            const float a[4] = {af.x, af.y, af.z, af.w};
            const float b[4] = {bf.x, bf.y, bf.z, bf.w};
            #pragma unroll
            for (int i = 0; i < 4; ++i)
                #pragma unroll
                for (int j = 0; j < 4; ++j)
                    o[i][j] += a[i] * b[j];
        }
        __syncthreads();   // before next restage
    }

    // write ctx [bh][s][d]
    #pragma unroll
    for (int i = 0; i < 4; ++i)
        *(float4*)(ctx + qbase + (long)(4 * ty + i) * HD + 4 * tx)
            = make_float4(o[i][0], o[i][1], o[i][2], o[i][3]);
}

// ---------------- output projection GEMM -------------------------------------
__global__ __launch_bounds__(256)
void outproj_kernel(const float* __restrict__ ctx,
                    const float* __restrict__ Wo,
                    const float* __restrict__ bo,
                    float* __restrict__ out)
{
    __shared__ float As[64][17];
    __shared__ float Bs[16][68];
    const int tx = threadIdx.x, ty = threadIdx.y;
    const int tid = ty * 16 + tx;
    const int bx = blockIdx.x, by = blockIdx.y;
    const int row0 = by * 64, col0 = bx * 64;
    float acc[4][4] = {};

    for (int kt = 0; kt < DM; kt += 16) {
        {
            const int idx = tid * 4;
            const int r = idx >> 4, kl = idx & 15;
            const int row = row0 + r;
            const int n = row >> 11, s = row & (S_LEN - 1);
            const int kk = kt + kl;
            const int h = kk >> 6, d = kk & 63;
            const float4 v = *(const float4*)(ctx + (((long)(n * NHEADS + h) * S_LEN + s) * HD + d));
            As[r][kl + 0] = v.x; As[r][kl + 1] = v.y; As[r][kl + 2] = v.z; As[r][kl + 3] = v.w;
        }
        {
            const int idx = tid * 4;
            const int k = idx >> 6, c = idx & 63;
            const float4 v = *(const float4*)(Wo + (long)(kt + k) * DM + col0 + c);
            Bs[k][c + 0] = v.x; Bs[k][c + 1] = v.y; Bs[k][c + 2] = v.z; Bs[k][c + 3] = v.w;
        }
        __syncthreads();
        #pragma unroll
        for (int k = 0; k < 16; ++k) {
            float a[4], b[4];
            #pragma unroll
            for (int i = 0; i < 4; ++i) a[i] = As[ty * 4 + i][k];
            #pragma unroll
            for (int j = 0; j < 4; ++j) b[j] = Bs[k][tx * 4 + j];
            #pragma unroll
            for (int i = 0; i < 4; ++i)
                #pragma unroll
                for (int j = 0; j < 4; ++j)
                    acc[i][j] += a[i] * b[j];
        }
        __syncthreads();
    }

    #pragma unroll
    for (int i = 0; i < 4; ++i) {
        const int row = row0 + ty * 4 + i;
        float* dst = out + (long)row * DM + col0 + tx * 4;
        dst[0] = acc[i][0] + bo[col0 + tx * 4 + 0];
        dst[1] = acc[i][1] + bo[col0 + tx * 4 + 1];
        dst[2] = acc[i][2] + bo[col0 + tx * 4 + 2];
        dst[3] = acc[i][3] + bo[col0 + tx * 4 + 3];
    }
}

extern "C" void kernel_launch(void* const* d_in, const int* in_sizes, int n_in,
                              void* d_out, int out_size, void* d_ws, size_t ws_size,
                              hipStream_t stream) {
    const float* x    = (const float*)d_in[0];
    const float* Wq   = (const float*)d_in[1];
    const float* bq   = (const float*)d_in[2];
    const float* Wk   = (const float*)d_in[3];
    const float* bk   = (const float*)d_in[4];
    const float* Wv   = (const float*)d_in[5];
    const float* bv   = (const float*)d_in[6];
    const float* Wo   = (const float*)d_in[7];
    const float* bo   = (const float*)d_in[8];
    const float* cosp = (const float*)d_in[9];
    const float* sinp = (const float*)d_in[10];
    // d_in[11] = mask (causal tril) — implemented analytically.

    float* out = (float*)d_out;
    float* ws  = (float*)d_ws;

    float* qT  = ws;
    float* kT  = ws + 4194304;
    float* vT  = ws + 8388608;
    float* ctx = ws + 12582912;

    float* hidden = out;
    float* attn   = out + (long)NROWS * DM;

    dim3 gblk(16, 16);
    dim3 ggrid(DM / 64, NROWS / 64);
    hipLaunchKernelGGL((proj_kernel<1>), ggrid, gblk, 0, stream, x, Wq, bq, cosp, sinp, qT);
    hipLaunchKernelGGL((proj_kernel<1>), ggrid, gblk, 0, stream, x, Wk, bk, cosp, sinp, kT);
    hipLaunchKernelGGL((proj_kernel<0>), ggrid, gblk, 0, stream, x, Wv, bv, cosp, sinp, vT);

    attn_tiled<<<NBATCH * NHEADS * 32, 256, 0, stream>>>(qT, kT, vT, attn, ctx);

    outproj_kernel<<<ggrid, gblk, 0, stream>>>(ctx, Wo, bo, hidden);
}